// Round 1
// baseline (4357.790 us; speedup 1.0000x reference)
//
#include <hip/hip_runtime.h>

// ---------------------------------------------------------------------------
// 2-layer GCN (PyG GCNConv semantics) for N=100000, E=1600000, 128->128->64.
//
// Round 1: correctness-first fp32 implementation.
//   deg -> dinv -> h = x@W1 -> edge scatter-add (atomics) -> +selfloop +b1,
//   ReLU, deterministic JAX dropout -> h2 = h@W2 -> scatter-add -> +selfloop+b2.
//
// Dropout mask reproduces jax.random.bernoulli(jax.random.key(42), 0.5, (N,128)).
// TF_VARIANT 0 = partitionable threefry (modern JAX default):
//   counter u64 = linear idx i; cipher inputs (hi,lo)=(0,i); draw = out0^out1.
// TF_VARIANT 1 = legacy split-halves layout (fallback if mask is wrong).
// keep iff (draw >> 31) == 0  (i.e. uniform u < 0.5).
// ---------------------------------------------------------------------------

#ifndef TF_VARIANT
#define TF_VARIANT 0
#endif

constexpr int NN   = 100000;
constexpr int NE   = 1600000;
constexpr int F_HID = 128;
constexpr int F_OUT = 64;

__device__ __forceinline__ unsigned tf_rotl(unsigned x, int r) {
  return (x << r) | (x >> (32 - r));
}

// Threefry-2x32, 20 rounds, key (0, 42) == jax.random.key(42)
__device__ __forceinline__ void threefry2x32_0_42(unsigned in0, unsigned in1,
                                                  unsigned& o0, unsigned& o1) {
  const unsigned K0 = 0u, K1 = 42u;
  const unsigned K2 = 0x1BD11BDAu ^ K0 ^ K1;
  unsigned x0 = in0 + K0, x1 = in1 + K1;
#define TFR(r) { x0 += x1; x1 = tf_rotl(x1, r); x1 ^= x0; }
  TFR(13) TFR(15) TFR(26) TFR(6)
  x0 += K1; x1 += K2 + 1u;
  TFR(17) TFR(29) TFR(16) TFR(24)
  x0 += K2; x1 += K0 + 2u;
  TFR(13) TFR(15) TFR(26) TFR(6)
  x0 += K0; x1 += K1 + 3u;
  TFR(17) TFR(29) TFR(16) TFR(24)
  x0 += K1; x1 += K2 + 4u;
  TFR(13) TFR(15) TFR(26) TFR(6)
  x0 += K2; x1 += K0 + 5u;
#undef TFR
  o0 = x0; o1 = x1;
}

__device__ __forceinline__ bool dropout_keep(unsigned i) {
#if TF_VARIANT == 0
  unsigned a, b; threefry2x32_0_42(0u, i, a, b);
  return ((a ^ b) >> 31) == 0u;
#else
  const unsigned HALF = (unsigned)(NN) * (unsigned)(F_HID) / 2u;
  unsigned a, b;
  if (i < HALF) { threefry2x32_0_42(i, HALF + i, a, b); return (a >> 31) == 0u; }
  else          { threefry2x32_0_42(i - HALF, i, a, b); return (b >> 31) == 0u; }
#endif
}

// ---------------------------------------------------------------------------

__global__ __launch_bounds__(256) void deg_kernel(const int* __restrict__ dst,
                                                  float* __restrict__ deg) {
  int e = blockIdx.x * 256 + threadIdx.x;
  if (e < NE) unsafeAtomicAdd(&deg[dst[e]], 1.0f);
}

__global__ __launch_bounds__(256) void dinv_kernel(float* __restrict__ degdinv) {
  int n = blockIdx.x * 256 + threadIdx.x;
  if (n < NN) degdinv[n] = rsqrtf(degdinv[n] + 1.0f);  // +1 self-loop
}

// H[rows x C] = X[rows x 128] @ W[128 x C], fp32, 64 rows per block.
template <int C>
__global__ __launch_bounds__(256) void gemm_kernel(const float* __restrict__ X,
                                                   const float* __restrict__ W,
                                                   float* __restrict__ H,
                                                   int nrows) {
  __shared__ float Ws[128 * C];
  __shared__ float Xs[64 * 128];
  const int row0 = blockIdx.x * 64;
  const int nr = min(64, nrows - row0);

  for (int t = threadIdx.x; t < 128 * C / 4; t += 256)
    ((float4*)Ws)[t] = ((const float4*)W)[t];
  for (int t = threadIdx.x; t < 64 * 128 / 4; t += 256) {
    int r = t >> 5;  // 32 float4 per row
    float4 v = make_float4(0.f, 0.f, 0.f, 0.f);
    if (r < nr) v = ((const float4*)(X + (size_t)row0 * 128))[t];
    ((float4*)Xs)[t] = v;
  }
  __syncthreads();

  constexpr int C4  = C / 4;        // float4 col-groups (32 or 16)
  constexpr int RG  = 256 / C4;     // row-group stride (8 or 16)
  constexpr int RPT = 64 / RG;      // rows per thread (8 or 4)
  const int c4 = threadIdx.x % C4;
  const int r0 = threadIdx.x / C4;

  float4 acc[RPT];
#pragma unroll
  for (int j = 0; j < RPT; j++) acc[j] = make_float4(0.f, 0.f, 0.f, 0.f);

  for (int k = 0; k < 128; k++) {
    float4 w = ((const float4*)(Ws + k * C))[c4];
#pragma unroll
    for (int j = 0; j < RPT; j++) {
      float xv = Xs[(r0 + j * RG) * 128 + k];
      acc[j].x = fmaf(xv, w.x, acc[j].x);
      acc[j].y = fmaf(xv, w.y, acc[j].y);
      acc[j].z = fmaf(xv, w.z, acc[j].z);
      acc[j].w = fmaf(xv, w.w, acc[j].w);
    }
  }
#pragma unroll
  for (int j = 0; j < RPT; j++) {
    int r = r0 + j * RG;
    if (r < nr) ((float4*)(H + (size_t)(row0 + r) * C))[c4] = acc[j];
  }
}

// Edge-parallel scatter: out[dst] += H[src] * dinv[src]*dinv[dst]
template <int C>
__global__ __launch_bounds__(256) void agg_kernel(const int* __restrict__ src,
                                                  const int* __restrict__ dst,
                                                  const float* __restrict__ dinv,
                                                  const float* __restrict__ H,
                                                  float* __restrict__ out) {
  constexpr int C4 = C / 4;
  int gid = blockIdx.x * 256 + threadIdx.x;
  if (gid >= NE * C4) return;
  int e  = gid / C4;
  int c4 = gid % C4;
  int s = src[e], d = dst[e];
  float nrm = dinv[s] * dinv[d];
  float4 h = ((const float4*)(H + (size_t)s * C))[c4];
  float* o = out + (size_t)d * C + c4 * 4;
  unsafeAtomicAdd(o + 0, h.x * nrm);
  unsafeAtomicAdd(o + 1, h.y * nrm);
  unsafeAtomicAdd(o + 2, h.z * nrm);
  unsafeAtomicAdd(o + 3, h.w * nrm);
}

// h = dropout(relu(agg + h*dinv^2 + b1)) written back in place over h
__global__ __launch_bounds__(256) void post1_kernel(const float* __restrict__ agg,
                                                    float* __restrict__ h,
                                                    const float* __restrict__ dinv,
                                                    const float* __restrict__ b1) {
  int i = blockIdx.x * 256 + threadIdx.x;
  if (i >= NN * F_HID) return;
  int n = i >> 7, f = i & 127;
  float di = dinv[n];
  float v = agg[i] + h[i] * di * di + b1[f];
  v = fmaxf(v, 0.0f);
  v = dropout_keep((unsigned)i) ? 2.0f * v : 0.0f;
  h[i] = v;
}

// out = out + h2*dinv^2 + b2
__global__ __launch_bounds__(256) void post2_kernel(const float* __restrict__ h2,
                                                    const float* __restrict__ dinv,
                                                    const float* __restrict__ b2,
                                                    float* __restrict__ out) {
  int i = blockIdx.x * 256 + threadIdx.x;
  if (i >= NN * F_OUT) return;
  int n = i >> 6, f = i & 63;
  float di = dinv[n];
  out[i] = out[i] + h2[i] * di * di + b2[f];
}

// ---------------------------------------------------------------------------

extern "C" void kernel_launch(void* const* d_in, const int* in_sizes, int n_in,
                              void* d_out, int out_size, void* d_ws, size_t ws_size,
                              hipStream_t stream) {
  const float* x  = (const float*)d_in[0];
  const int*   ei = (const int*)d_in[1];   // [2, E] row-major
  const float* W1 = (const float*)d_in[2];
  const float* b1 = (const float*)d_in[3];
  const float* W2 = (const float*)d_in[4];
  const float* b2 = (const float*)d_in[5];
  float* out = (float*)d_out;

  const int* src = ei;
  const int* dst = ei + NE;

  // workspace: dinv[N] | h[N*128] | agg[N*128] (agg reused for h2[N*64])
  float* dinv = (float*)d_ws;
  float* h    = dinv + NN;
  float* agg  = h + (size_t)NN * F_HID;
  float* h2   = agg;  // reuse after post1 consumed agg

  // degree (in-degree over dst) -> dinv
  hipMemsetAsync(dinv, 0, NN * sizeof(float), stream);
  deg_kernel<<<(NE + 255) / 256, 256, 0, stream>>>(dst, dinv);
  dinv_kernel<<<(NN + 255) / 256, 256, 0, stream>>>(dinv);

  // layer 1
  gemm_kernel<128><<<(NN + 63) / 64, 256, 0, stream>>>(x, W1, h, NN);
  hipMemsetAsync(agg, 0, (size_t)NN * F_HID * sizeof(float), stream);
  agg_kernel<128><<<(NE * 32 + 255) / 256, 256, 0, stream>>>(src, dst, dinv, h, agg);
  post1_kernel<<<(NN * F_HID + 255) / 256, 256, 0, stream>>>(agg, h, dinv, b1);

  // layer 2
  gemm_kernel<64><<<(NN + 63) / 64, 256, 0, stream>>>(h, W2, h2, NN);
  hipMemsetAsync(out, 0, (size_t)NN * F_OUT * sizeof(float), stream);
  agg_kernel<64><<<(NE * 16 + 255) / 256, 256, 0, stream>>>(src, dst, dinv, h2, out);
  post2_kernel<<<(NN * F_OUT + 255) / 256, 256, 0, stream>>>(h2, dinv, b2, out);
}

// Round 5
// 721.896 us; speedup vs baseline: 6.0366x; 6.0366x over previous
//
#include <hip/hip_runtime.h>

// ---------------------------------------------------------------------------
// 2-layer GCN (PyG GCNConv) N=100000, E=1600000, 128->128->64.
//
// Round 5 == round 2 kernel, resubmitted (rounds 2-4 all hit
// GPUAcquisitionTimeout before running; no measurements yet).
// CSR-gather instead of atomic scatter; bf16 intermediate storage.
//   hist(dst) -> exclusive scan -> permute edges into dst-sorted order
//   h  = x@W1   (fp32 compute, bf16 store)
//   hd = dropout(relu(gather(h) + selfloop + b1))   [bf16]
//   h2 = hd@W2  (bf16 in, fp32 compute, bf16 store)
//   out = gather(h2) + selfloop + b2                [fp32]
// Dropout reproduces jax.random.bernoulli(key(42), 0.5) — partitionable
// threefry, draw_i = o0^o1 of TF2x32(0, i), keep iff top bit clear.
// ---------------------------------------------------------------------------

constexpr int NN    = 100000;
constexpr int NE    = 1600000;
constexpr int F_HID = 128;
constexpr int F_OUT = 64;
constexpr int SCAN_CHUNK = 2048;                    // elems per scan block
constexpr int NSCAN = (NN + SCAN_CHUNK - 1) / SCAN_CHUNK;  // 49

__device__ __forceinline__ float bf2f(unsigned short u) {
  return __uint_as_float(((unsigned)u) << 16);
}
__device__ __forceinline__ unsigned short f2bf(float f) {
  unsigned x = __float_as_uint(f);
  return (unsigned short)((x + 0x7fffu + ((x >> 16) & 1u)) >> 16);
}

__device__ __forceinline__ unsigned tf_rotl(unsigned x, int r) {
  return (x << r) | (x >> (32 - r));
}

// Threefry-2x32, 20 rounds, key (0, 42) == jax.random.key(42)
__device__ __forceinline__ void threefry2x32_0_42(unsigned in0, unsigned in1,
                                                  unsigned& o0, unsigned& o1) {
  const unsigned K0 = 0u, K1 = 42u;
  const unsigned K2 = 0x1BD11BDAu ^ K0 ^ K1;
  unsigned x0 = in0 + K0, x1 = in1 + K1;
#define TFR(r) { x0 += x1; x1 = tf_rotl(x1, r); x1 ^= x0; }
  TFR(13) TFR(15) TFR(26) TFR(6)
  x0 += K1; x1 += K2 + 1u;
  TFR(17) TFR(29) TFR(16) TFR(24)
  x0 += K2; x1 += K0 + 2u;
  TFR(13) TFR(15) TFR(26) TFR(6)
  x0 += K0; x1 += K1 + 3u;
  TFR(17) TFR(29) TFR(16) TFR(24)
  x0 += K1; x1 += K2 + 4u;
  TFR(13) TFR(15) TFR(26) TFR(6)
  x0 += K2; x1 += K0 + 5u;
#undef TFR
  o0 = x0; o1 = x1;
}

__device__ __forceinline__ bool dropout_keep(unsigned i) {
  unsigned a, b; threefry2x32_0_42(0u, i, a, b);
  return ((a ^ b) >> 31) == 0u;
}

// ---------------------------------------------------------------------------
// CSR build
// ---------------------------------------------------------------------------

__global__ __launch_bounds__(256) void hist_kernel(const int* __restrict__ dst,
                                                   int* __restrict__ cnt) {
  int e = blockIdx.x * 256 + threadIdx.x;
  if (e < NE) atomicAdd(&cnt[dst[e]], 1);
}

// per-block exclusive scan of cnt -> off (block-local), block totals, dinv
__global__ __launch_bounds__(256) void scan1_kernel(const int* __restrict__ cnt,
                                                    int* __restrict__ off,
                                                    int* __restrict__ blksum,
                                                    float* __restrict__ dinv) {
  __shared__ int tsum[256];
  const int base = blockIdx.x * SCAN_CHUNK + threadIdx.x * 8;
  int v[8]; int s = 0;
#pragma unroll
  for (int j = 0; j < 8; j++) {
    int idx = base + j;
    v[j] = (idx < NN) ? cnt[idx] : 0;
    s += v[j];
    if (idx < NN) dinv[idx] = rsqrtf((float)v[j] + 1.0f);  // +1 self-loop
  }
  tsum[threadIdx.x] = s;
  __syncthreads();
  for (int d = 1; d < 256; d <<= 1) {
    int t = (threadIdx.x >= d) ? tsum[threadIdx.x - d] : 0;
    __syncthreads();
    tsum[threadIdx.x] += t;
    __syncthreads();
  }
  int run = tsum[threadIdx.x] - s;  // exclusive
  if (threadIdx.x == 255) blksum[blockIdx.x] = tsum[255];
#pragma unroll
  for (int j = 0; j < 8; j++) {
    int idx = base + j;
    if (idx < NN) { off[idx] = run; run += v[j]; }
  }
}

__global__ void scan2_kernel(int* __restrict__ blksum, int* __restrict__ off) {
  if (threadIdx.x == 0) {
    int run = 0;
    for (int i = 0; i < NSCAN; i++) { int t = blksum[i]; blksum[i] = run; run += t; }
    off[NN] = NE;
  }
}

__global__ __launch_bounds__(256) void scan3_kernel(int* __restrict__ off,
                                                    const int* __restrict__ blksum) {
  const int base = blockIdx.x * SCAN_CHUNK + threadIdx.x * 8;
  const int add = blksum[blockIdx.x];
#pragma unroll
  for (int j = 0; j < 8; j++) {
    int idx = base + j;
    if (idx < NN) off[idx] += add;
  }
}

// scatter edges into dst-sorted order; precompute per-edge norm
__global__ __launch_bounds__(256) void permute_kernel(const int* __restrict__ src,
                                                      const int* __restrict__ dst,
                                                      const int* __restrict__ off,
                                                      int* __restrict__ cur,
                                                      const float* __restrict__ dinv,
                                                      int* __restrict__ srcs,
                                                      float* __restrict__ nrms) {
  int e = blockIdx.x * 256 + threadIdx.x;
  if (e >= NE) return;
  int d = dst[e], s = src[e];
  int p = off[d] + atomicAdd(&cur[d], 1);
  srcs[p] = s;
  nrms[p] = dinv[s] * dinv[d];
}

// ---------------------------------------------------------------------------
// GEMM: H[rows x C] = X[rows x 128] @ W[128 x C]; fp32 compute.
// BF16_IN: X rows are packed bf16 pairs. BF16_OUT: H rows packed bf16 pairs.
// ---------------------------------------------------------------------------

template <int C, bool BF16_IN, bool BF16_OUT>
__global__ __launch_bounds__(256) void gemm_kernel(const void* __restrict__ Xv,
                                                   const float* __restrict__ W,
                                                   void* __restrict__ Hv,
                                                   int nrows) {
  __shared__ float Ws[128 * C];
  __shared__ float Xs[64 * 128];
  const int row0 = blockIdx.x * 64;
  const int nr = min(64, nrows - row0);

  for (int t = threadIdx.x; t < 128 * C / 4; t += 256)
    ((float4*)Ws)[t] = ((const float4*)W)[t];

  if (BF16_IN) {
    const unsigned* X = (const unsigned*)Xv + (size_t)row0 * 64;
    for (int t = threadIdx.x; t < 64 * 64; t += 256) {
      int r = t >> 6, u = t & 63;
      unsigned p = (r < nr) ? X[r * 64 + u] : 0u;
      Xs[r * 128 + 2 * u]     = bf2f((unsigned short)(p & 0xffffu));
      Xs[r * 128 + 2 * u + 1] = bf2f((unsigned short)(p >> 16));
    }
  } else {
    const float* X = (const float*)Xv + (size_t)row0 * 128;
    for (int t = threadIdx.x; t < 64 * 128 / 4; t += 256) {
      int r = t >> 5;
      float4 v = make_float4(0.f, 0.f, 0.f, 0.f);
      if (r < nr) v = ((const float4*)X)[t];
      ((float4*)Xs)[t] = v;
    }
  }
  __syncthreads();

  constexpr int C4  = C / 4;
  constexpr int RG  = 256 / C4;
  constexpr int RPT = 64 / RG;
  const int c4 = threadIdx.x % C4;
  const int r0 = threadIdx.x / C4;

  float4 acc[RPT];
#pragma unroll
  for (int j = 0; j < RPT; j++) acc[j] = make_float4(0.f, 0.f, 0.f, 0.f);

  for (int k = 0; k < 128; k++) {
    float4 w = ((const float4*)(Ws + k * C))[c4];
#pragma unroll
    for (int j = 0; j < RPT; j++) {
      float xv = Xs[(r0 + j * RG) * 128 + k];
      acc[j].x = fmaf(xv, w.x, acc[j].x);
      acc[j].y = fmaf(xv, w.y, acc[j].y);
      acc[j].z = fmaf(xv, w.z, acc[j].z);
      acc[j].w = fmaf(xv, w.w, acc[j].w);
    }
  }
#pragma unroll
  for (int j = 0; j < RPT; j++) {
    int r = r0 + j * RG;
    if (r < nr) {
      if (BF16_OUT) {
        unsigned p0 = ((unsigned)f2bf(acc[j].y) << 16) | f2bf(acc[j].x);
        unsigned p1 = ((unsigned)f2bf(acc[j].w) << 16) | f2bf(acc[j].z);
        *(uint2*)((unsigned*)Hv + (size_t)(row0 + r) * (C / 2) + c4 * 2) =
            make_uint2(p0, p1);
      } else {
        ((float4*)((float*)Hv + (size_t)(row0 + r) * C))[c4] = acc[j];
      }
    }
  }
}

// ---------------------------------------------------------------------------
// Gather layer 1: hd = dropout(relu(sum_e h[src]*nrm + h[nid]*dinv^2 + b1))
// 64 threads (1 wave) per node; each thread owns a bf16 pair (2 channels).
// ---------------------------------------------------------------------------

__global__ __launch_bounds__(256) void gather1_kernel(const int* __restrict__ off,
                                                      const int* __restrict__ srcs,
                                                      const float* __restrict__ nrms,
                                                      const unsigned* __restrict__ hb,
                                                      const float* __restrict__ dinv,
                                                      const float* __restrict__ b1,
                                                      unsigned* __restrict__ hd) {
  int nid = blockIdx.x * 4 + (threadIdx.x >> 6);
  if (nid >= NN) return;
  int c = threadIdx.x & 63;
  float di = dinv[nid];
  unsigned hp = hb[(size_t)nid * 64 + c];
  float a0 = bf2f((unsigned short)(hp & 0xffffu)) * di * di;
  float a1 = bf2f((unsigned short)(hp >> 16)) * di * di;
  int beg = off[nid], end = off[nid + 1];
  for (int e = beg; e < end; e++) {
    int s = srcs[e];
    float w = nrms[e];
    unsigned p = hb[(size_t)s * 64 + c];
    a0 = fmaf(bf2f((unsigned short)(p & 0xffffu)), w, a0);
    a1 = fmaf(bf2f((unsigned short)(p >> 16)), w, a1);
  }
  a0 += b1[2 * c];
  a1 += b1[2 * c + 1];
  a0 = fmaxf(a0, 0.f);
  a1 = fmaxf(a1, 0.f);
  unsigned i0 = (unsigned)nid * 128u + 2u * (unsigned)c;
  a0 = dropout_keep(i0)      ? 2.f * a0 : 0.f;
  a1 = dropout_keep(i0 + 1u) ? 2.f * a1 : 0.f;
  hd[(size_t)nid * 64 + c] = ((unsigned)f2bf(a1) << 16) | f2bf(a0);
}

// ---------------------------------------------------------------------------
// Gather layer 2: out = sum_e h2[src]*nrm + h2[nid]*dinv^2 + b2   (fp32 out)
// 64 threads (1 wave) per node; 1 channel per thread.
// ---------------------------------------------------------------------------

__global__ __launch_bounds__(256) void gather2_kernel(const int* __restrict__ off,
                                                      const int* __restrict__ srcs,
                                                      const float* __restrict__ nrms,
                                                      const unsigned short* __restrict__ h2b,
                                                      const float* __restrict__ dinv,
                                                      const float* __restrict__ b2,
                                                      float* __restrict__ out) {
  int nid = blockIdx.x * 4 + (threadIdx.x >> 6);
  if (nid >= NN) return;
  int c = threadIdx.x & 63;
  float di = dinv[nid];
  float acc = bf2f(h2b[(size_t)nid * 64 + c]) * di * di;
  int beg = off[nid], end = off[nid + 1];
  for (int e = beg; e < end; e++) {
    acc = fmaf(bf2f(h2b[(size_t)srcs[e] * 64 + c]), nrms[e], acc);
  }
  out[(size_t)nid * 64 + c] = acc + b2[c];
}

// ---------------------------------------------------------------------------

extern "C" void kernel_launch(void* const* d_in, const int* in_sizes, int n_in,
                              void* d_out, int out_size, void* d_ws, size_t ws_size,
                              hipStream_t stream) {
  const float* x  = (const float*)d_in[0];
  const int*   ei = (const int*)d_in[1];
  const float* W1 = (const float*)d_in[2];
  const float* b1 = (const float*)d_in[3];
  const float* W2 = (const float*)d_in[4];
  const float* b2 = (const float*)d_in[5];
  float* out = (float*)d_out;

  const int* src = ei;
  const int* dst = ei + NE;

  // workspace layout (16B aligned chunks)
  char* p = (char*)d_ws;
  auto take = [&](size_t bytes) { char* q = p; p += (bytes + 15) & ~size_t(15); return q; };
  int*      cnt    = (int*)take(sizeof(int) * NN);          // also permute cursor
  int*      off    = (int*)take(sizeof(int) * (NN + 1));
  int*      blksum = (int*)take(sizeof(int) * NSCAN);
  float*    dinv   = (float*)take(sizeof(float) * NN);
  int*      srcs   = (int*)take(sizeof(int) * NE);
  float*    nrms   = (float*)take(sizeof(float) * NE);
  unsigned* hb     = (unsigned*)take(sizeof(unsigned) * (size_t)NN * 64);   // h  bf16x2
  unsigned* hd     = (unsigned*)take(sizeof(unsigned) * (size_t)NN * 64);   // hd bf16x2
  unsigned* h2b    = (unsigned*)take(sizeof(unsigned) * (size_t)NN * 32);   // h2 bf16x2

  // CSR build
  hipMemsetAsync(cnt, 0, sizeof(int) * NN, stream);
  hist_kernel<<<(NE + 255) / 256, 256, 0, stream>>>(dst, cnt);
  scan1_kernel<<<NSCAN, 256, 0, stream>>>(cnt, off, blksum, dinv);
  scan2_kernel<<<1, 64, 0, stream>>>(blksum, off);
  scan3_kernel<<<NSCAN, 256, 0, stream>>>(off, blksum);
  hipMemsetAsync(cnt, 0, sizeof(int) * NN, stream);
  permute_kernel<<<(NE + 255) / 256, 256, 0, stream>>>(src, dst, off, cnt, dinv, srcs, nrms);

  // layer 1
  gemm_kernel<128, false, true><<<(NN + 63) / 64, 256, 0, stream>>>(x, W1, hb, NN);
  gather1_kernel<<<(NN + 3) / 4, 256, 0, stream>>>(off, srcs, nrms, hb, dinv, b1, hd);

  // layer 2
  gemm_kernel<64, true, true><<<(NN + 63) / 64, 256, 0, stream>>>(hd, W2, h2b, NN);
  gather2_kernel<<<(NN + 3) / 4, 256, 0, stream>>>(off, srcs, nrms, (const unsigned short*)h2b, dinv, b2, out);
}

// Round 11
// 484.295 us; speedup vs baseline: 8.9982x; 1.4906x over previous
//
#include <hip/hip_runtime.h>

// ---------------------------------------------------------------------------
// 2-layer GCN (PyG GCNConv) N=100000, E=1600000, 128->128->64.
//
// Round 11 == round 6 kernel resubmitted (rounds 6-10 hit GPUAcquisitionTimeout;
// never ran). (a) MFMA bf16 GEMMs (16x16x32, padded-LDS stride 136 to kill
// bank conflicts), (b) gather loops unrolled x4 for memory-level parallelism.
// Pipeline: CSR build -> h=x@W1 (MFMA) -> gather1(+relu+bias+dropout, bf16)
//        -> h2=hd@W2 (MFMA) -> gather2(+bias, fp32 out).
// Dropout = jax.random.bernoulli(key(42),0.5), partitionable threefry:
// draw_i = o0^o1 of TF2x32(0,i), keep iff top bit clear.  [verified r5]
// ---------------------------------------------------------------------------

constexpr int NN    = 100000;
constexpr int NE    = 1600000;
constexpr int SCAN_CHUNK = 2048;
constexpr int NSCAN = (NN + SCAN_CHUNK - 1) / SCAN_CHUNK;  // 49

typedef __attribute__((ext_vector_type(8))) short short8v;
typedef __attribute__((ext_vector_type(4))) float f32x4;

__device__ __forceinline__ float bf2f(unsigned short u) {
  return __uint_as_float(((unsigned)u) << 16);
}
__device__ __forceinline__ unsigned short f2bf(float f) {
  unsigned x = __float_as_uint(f);
  return (unsigned short)((x + 0x7fffu + ((x >> 16) & 1u)) >> 16);
}
__device__ __forceinline__ float lo16(unsigned p) { return bf2f((unsigned short)(p & 0xffffu)); }
__device__ __forceinline__ float hi16(unsigned p) { return bf2f((unsigned short)(p >> 16)); }

__device__ __forceinline__ unsigned tf_rotl(unsigned x, int r) {
  return (x << r) | (x >> (32 - r));
}

// Threefry-2x32, 20 rounds, key (0, 42) == jax.random.key(42)
__device__ __forceinline__ void threefry2x32_0_42(unsigned in0, unsigned in1,
                                                  unsigned& o0, unsigned& o1) {
  const unsigned K0 = 0u, K1 = 42u;
  const unsigned K2 = 0x1BD11BDAu ^ K0 ^ K1;
  unsigned x0 = in0 + K0, x1 = in1 + K1;
#define TFR(r) { x0 += x1; x1 = tf_rotl(x1, r); x1 ^= x0; }
  TFR(13) TFR(15) TFR(26) TFR(6)
  x0 += K1; x1 += K2 + 1u;
  TFR(17) TFR(29) TFR(16) TFR(24)
  x0 += K2; x1 += K0 + 2u;
  TFR(13) TFR(15) TFR(26) TFR(6)
  x0 += K0; x1 += K1 + 3u;
  TFR(17) TFR(29) TFR(16) TFR(24)
  x0 += K1; x1 += K2 + 4u;
  TFR(13) TFR(15) TFR(26) TFR(6)
  x0 += K2; x1 += K0 + 5u;
#undef TFR
  o0 = x0; o1 = x1;
}

__device__ __forceinline__ bool dropout_keep(unsigned i) {
  unsigned a, b; threefry2x32_0_42(0u, i, a, b);
  return ((a ^ b) >> 31) == 0u;
}

// ---------------------------------------------------------------------------
// CSR build
// ---------------------------------------------------------------------------

__global__ __launch_bounds__(256) void hist_kernel(const int* __restrict__ dst,
                                                   int* __restrict__ cnt) {
  int e = blockIdx.x * 256 + threadIdx.x;
  if (e < NE) atomicAdd(&cnt[dst[e]], 1);
}

__global__ __launch_bounds__(256) void scan1_kernel(const int* __restrict__ cnt,
                                                    int* __restrict__ off,
                                                    int* __restrict__ blksum,
                                                    float* __restrict__ dinv) {
  __shared__ int tsum[256];
  const int base = blockIdx.x * SCAN_CHUNK + threadIdx.x * 8;
  int v[8]; int s = 0;
#pragma unroll
  for (int j = 0; j < 8; j++) {
    int idx = base + j;
    v[j] = (idx < NN) ? cnt[idx] : 0;
    s += v[j];
    if (idx < NN) dinv[idx] = rsqrtf((float)v[j] + 1.0f);  // +1 self-loop
  }
  tsum[threadIdx.x] = s;
  __syncthreads();
  for (int d = 1; d < 256; d <<= 1) {
    int t = (threadIdx.x >= d) ? tsum[threadIdx.x - d] : 0;
    __syncthreads();
    tsum[threadIdx.x] += t;
    __syncthreads();
  }
  int run = tsum[threadIdx.x] - s;  // exclusive
  if (threadIdx.x == 255) blksum[blockIdx.x] = tsum[255];
#pragma unroll
  for (int j = 0; j < 8; j++) {
    int idx = base + j;
    if (idx < NN) { off[idx] = run; run += v[j]; }
  }
}

__global__ void scan2_kernel(int* __restrict__ blksum, int* __restrict__ off) {
  if (threadIdx.x == 0) {
    int run = 0;
    for (int i = 0; i < NSCAN; i++) { int t = blksum[i]; blksum[i] = run; run += t; }
    off[NN] = NE;
  }
}

__global__ __launch_bounds__(256) void scan3_kernel(int* __restrict__ off,
                                                    const int* __restrict__ blksum) {
  const int base = blockIdx.x * SCAN_CHUNK + threadIdx.x * 8;
  const int add = blksum[blockIdx.x];
#pragma unroll
  for (int j = 0; j < 8; j++) {
    int idx = base + j;
    if (idx < NN) off[idx] += add;
  }
}

__global__ __launch_bounds__(256) void permute_kernel(const int* __restrict__ src,
                                                      const int* __restrict__ dst,
                                                      const int* __restrict__ off,
                                                      int* __restrict__ cur,
                                                      const float* __restrict__ dinv,
                                                      int* __restrict__ srcs,
                                                      float* __restrict__ nrms) {
  int e = blockIdx.x * 256 + threadIdx.x;
  if (e >= NE) return;
  int d = dst[e], s = src[e];
  int p = off[d] + atomicAdd(&cur[d], 1);
  srcs[p] = s;
  nrms[p] = dinv[s] * dinv[d];
}

// ---------------------------------------------------------------------------
// MFMA GEMM: H[rows x C] = X[rows x 128] @ W[128 x C], bf16 MFMA 16x16x32.
// 64 rows/block, 256 thr (4 waves); wave w owns rows w*16..w*16+15, all C cols.
// LDS stride 136 ushorts (pad) => 2-way-max bank aliasing on b128 frag reads.
// Fragment layouts (m89-verified): A row=lane&15, k=(lane>>4)*8+j (contig);
// B (from W^T in LDS) col=lane&15, same k; D col=lane&15, row=(lane>>4)*4+r.
// ---------------------------------------------------------------------------

template <int C, bool BF16_IN>
__global__ __launch_bounds__(256) void gemm_mfma_kernel(const void* __restrict__ Xv,
                                                        const float* __restrict__ W,
                                                        unsigned short* __restrict__ H,
                                                        int nrows) {
  constexpr int STR = 136;
  __shared__ unsigned short Xs[64 * STR];
  __shared__ unsigned short Wt[C * STR];   // Wt[n][k] = W[k][n]
  const int row0 = blockIdx.x * 64;
  const int nr = min(64, nrows - row0);
  const int tid = threadIdx.x;

  // stage W^T as bf16: thread t handles (n, kk): k = 2*kk, 2*kk+1
  for (int t = tid; t < C * 64; t += 256) {
    int n = t % C, kk = t / C;
    unsigned pk = ((unsigned)f2bf(W[(2 * kk + 1) * C + n]) << 16) | f2bf(W[(2 * kk) * C + n]);
    *(unsigned*)&Wt[n * STR + 2 * kk] = pk;
  }
  // stage X as bf16: thread t handles (row, kp): k = 2*kp, 2*kp+1
  if (BF16_IN) {
    const unsigned* X = (const unsigned*)Xv + (size_t)row0 * 64;
    for (int t = tid; t < 64 * 64; t += 256) {
      int r = t >> 6, kp = t & 63;
      unsigned p = (r < nr) ? X[r * 64 + kp] : 0u;
      *(unsigned*)&Xs[r * STR + 2 * kp] = p;
    }
  } else {
    const float* X = (const float*)Xv + (size_t)row0 * 128;
    for (int t = tid; t < 64 * 64; t += 256) {
      int r = t >> 6, kp = t & 63;
      unsigned p = 0u;
      if (r < nr) {
        float2 v = *(const float2*)&X[r * 128 + 2 * kp];
        p = ((unsigned)f2bf(v.y) << 16) | f2bf(v.x);
      }
      *(unsigned*)&Xs[r * STR + 2 * kp] = p;
    }
  }
  __syncthreads();

  const int w  = tid >> 6;
  const int l  = tid & 63;
  const int lr = l & 15;
  const int lk = l >> 4;
  constexpr int NT = C / 16;

  f32x4 acc[NT];
#pragma unroll
  for (int nt = 0; nt < NT; nt++) acc[nt] = (f32x4){0.f, 0.f, 0.f, 0.f};

  short8v afr[4];
  const int arow = w * 16 + lr;
#pragma unroll
  for (int ks = 0; ks < 4; ks++)
    afr[ks] = *(const short8v*)&Xs[arow * STR + ks * 32 + lk * 8];

#pragma unroll
  for (int nt = 0; nt < NT; nt++) {
    const int ncol = nt * 16 + lr;
#pragma unroll
    for (int ks = 0; ks < 4; ks++) {
      short8v bfr = *(const short8v*)&Wt[ncol * STR + ks * 32 + lk * 8];
      acc[nt] = __builtin_amdgcn_mfma_f32_16x16x32_bf16(afr[ks], bfr, acc[nt], 0, 0, 0);
    }
  }

#pragma unroll
  for (int nt = 0; nt < NT; nt++) {
#pragma unroll
    for (int r = 0; r < 4; r++) {
      int row = w * 16 + lk * 4 + r;
      if (row < nr) H[(size_t)(row0 + row) * C + nt * 16 + lr] = f2bf(acc[nt][r]);
    }
  }
}

// ---------------------------------------------------------------------------
// Gather layer 1 (unroll x4): hd = dropout(relu(sum h[src]*nrm + self + b1))
// 1 wave per node, 2 bf16 channels per lane.
// ---------------------------------------------------------------------------

__global__ __launch_bounds__(256) void gather1_kernel(const int* __restrict__ off,
                                                      const int* __restrict__ srcs,
                                                      const float* __restrict__ nrms,
                                                      const unsigned* __restrict__ hb,
                                                      const float* __restrict__ dinv,
                                                      const float* __restrict__ b1,
                                                      unsigned* __restrict__ hd) {
  int nid = blockIdx.x * 4 + (threadIdx.x >> 6);
  if (nid >= NN) return;
  int c = threadIdx.x & 63;
  float di = dinv[nid];
  unsigned hp = hb[(size_t)nid * 64 + c];
  float a0 = lo16(hp) * di * di;
  float a1 = hi16(hp) * di * di;
  int beg = off[nid], end = off[nid + 1];
  int e = beg;
  for (; e + 4 <= end; e += 4) {
    int s0 = srcs[e], s1 = srcs[e + 1], s2 = srcs[e + 2], s3 = srcs[e + 3];
    float w0 = nrms[e], w1 = nrms[e + 1], w2 = nrms[e + 2], w3 = nrms[e + 3];
    unsigned p0 = hb[(size_t)s0 * 64 + c];
    unsigned p1 = hb[(size_t)s1 * 64 + c];
    unsigned p2 = hb[(size_t)s2 * 64 + c];
    unsigned p3 = hb[(size_t)s3 * 64 + c];
    a0 = fmaf(lo16(p0), w0, a0); a1 = fmaf(hi16(p0), w0, a1);
    a0 = fmaf(lo16(p1), w1, a0); a1 = fmaf(hi16(p1), w1, a1);
    a0 = fmaf(lo16(p2), w2, a0); a1 = fmaf(hi16(p2), w2, a1);
    a0 = fmaf(lo16(p3), w3, a0); a1 = fmaf(hi16(p3), w3, a1);
  }
  for (; e < end; e++) {
    int s = srcs[e];
    float w = nrms[e];
    unsigned p = hb[(size_t)s * 64 + c];
    a0 = fmaf(lo16(p), w, a0);
    a1 = fmaf(hi16(p), w, a1);
  }
  a0 += b1[2 * c];
  a1 += b1[2 * c + 1];
  a0 = fmaxf(a0, 0.f);
  a1 = fmaxf(a1, 0.f);
  unsigned i0 = (unsigned)nid * 128u + 2u * (unsigned)c;
  a0 = dropout_keep(i0)      ? 2.f * a0 : 0.f;
  a1 = dropout_keep(i0 + 1u) ? 2.f * a1 : 0.f;
  hd[(size_t)nid * 64 + c] = ((unsigned)f2bf(a1) << 16) | f2bf(a0);
}

// ---------------------------------------------------------------------------
// Gather layer 2 (unroll x4): out = sum h2[src]*nrm + self + b2   (fp32 out)
// 1 wave per node, 1 channel per lane.
// ---------------------------------------------------------------------------

__global__ __launch_bounds__(256) void gather2_kernel(const int* __restrict__ off,
                                                      const int* __restrict__ srcs,
                                                      const float* __restrict__ nrms,
                                                      const unsigned short* __restrict__ h2b,
                                                      const float* __restrict__ dinv,
                                                      const float* __restrict__ b2,
                                                      float* __restrict__ out) {
  int nid = blockIdx.x * 4 + (threadIdx.x >> 6);
  if (nid >= NN) return;
  int c = threadIdx.x & 63;
  float di = dinv[nid];
  float acc = bf2f(h2b[(size_t)nid * 64 + c]) * di * di;
  int beg = off[nid], end = off[nid + 1];
  int e = beg;
  for (; e + 4 <= end; e += 4) {
    int s0 = srcs[e], s1 = srcs[e + 1], s2 = srcs[e + 2], s3 = srcs[e + 3];
    float w0 = nrms[e], w1 = nrms[e + 1], w2 = nrms[e + 2], w3 = nrms[e + 3];
    float v0 = bf2f(h2b[(size_t)s0 * 64 + c]);
    float v1 = bf2f(h2b[(size_t)s1 * 64 + c]);
    float v2 = bf2f(h2b[(size_t)s2 * 64 + c]);
    float v3 = bf2f(h2b[(size_t)s3 * 64 + c]);
    acc = fmaf(v0, w0, acc);
    acc = fmaf(v1, w1, acc);
    acc = fmaf(v2, w2, acc);
    acc = fmaf(v3, w3, acc);
  }
  for (; e < end; e++) {
    acc = fmaf(bf2f(h2b[(size_t)srcs[e] * 64 + c]), nrms[e], acc);
  }
  out[(size_t)nid * 64 + c] = acc + b2[c];
}

// ---------------------------------------------------------------------------

extern "C" void kernel_launch(void* const* d_in, const int* in_sizes, int n_in,
                              void* d_out, int out_size, void* d_ws, size_t ws_size,
                              hipStream_t stream) {
  const float* x  = (const float*)d_in[0];
  const int*   ei = (const int*)d_in[1];
  const float* W1 = (const float*)d_in[2];
  const float* b1 = (const float*)d_in[3];
  const float* W2 = (const float*)d_in[4];
  const float* b2 = (const float*)d_in[5];
  float* out = (float*)d_out;

  const int* src = ei;
  const int* dst = ei + NE;

  char* p = (char*)d_ws;
  auto take = [&](size_t bytes) { char* q = p; p += (bytes + 15) & ~size_t(15); return q; };
  int*      cnt    = (int*)take(sizeof(int) * NN);
  int*      off    = (int*)take(sizeof(int) * (NN + 1));
  int*      blksum = (int*)take(sizeof(int) * NSCAN);
  float*    dinv   = (float*)take(sizeof(float) * NN);
  int*      srcs   = (int*)take(sizeof(int) * NE);
  float*    nrms   = (float*)take(sizeof(float) * NE);
  unsigned* hb     = (unsigned*)take(sizeof(unsigned) * (size_t)NN * 64);   // h  bf16x2
  unsigned* hd     = (unsigned*)take(sizeof(unsigned) * (size_t)NN * 64);   // hd bf16x2
  unsigned* h2b    = (unsigned*)take(sizeof(unsigned) * (size_t)NN * 32);   // h2 bf16x2

  // CSR build
  hipMemsetAsync(cnt, 0, sizeof(int) * NN, stream);
  hist_kernel<<<(NE + 255) / 256, 256, 0, stream>>>(dst, cnt);
  scan1_kernel<<<NSCAN, 256, 0, stream>>>(cnt, off, blksum, dinv);
  scan2_kernel<<<1, 64, 0, stream>>>(blksum, off);
  scan3_kernel<<<NSCAN, 256, 0, stream>>>(off, blksum);
  hipMemsetAsync(cnt, 0, sizeof(int) * NN, stream);
  permute_kernel<<<(NE + 255) / 256, 256, 0, stream>>>(src, dst, off, cnt, dinv, srcs, nrms);

  // layer 1
  gemm_mfma_kernel<128, false><<<(NN + 63) / 64, 256, 0, stream>>>(
      x, W1, (unsigned short*)hb, NN);
  gather1_kernel<<<(NN + 3) / 4, 256, 0, stream>>>(off, srcs, nrms, hb, dinv, b1, hd);

  // layer 2
  gemm_mfma_kernel<64, true><<<(NN + 63) / 64, 256, 0, stream>>>(
      hd, W2, (unsigned short*)h2b, NN);
  gather2_kernel<<<(NN + 3) / 4, 256, 0, stream>>>(
      off, srcs, nrms, (const unsigned short*)h2b, dinv, b2, out);
}